// Round 3
// 387.548 us; speedup vs baseline: 1.0076x; 1.0076x over previous
//
#include <hip/hip_runtime.h>

// ---------------------------------------------------------------------------
// RelativeAttention: L=2048, B=2, HID=1024, H=16, DH=64, P=50
//   q,k,v = x @ W^T + b            (bf16 MFMA GEMM, fp32 accumulate)
//   attn  = softmax((QK^T + Sr_gather)/8),  Sr[q,j] = Q[q]·rel_k[j]
//   out_h = attn@V + T@rel_v,      T[q,j] = sum of p over bucket j
//           (middle buckets j in [1,99] hit EXACTLY once -> plain stores)
//   out   = out_h @ Wo^T + bo      (written [L,B,HID])
// R10 = R7 attention (verified 162us, passing) + coalesced MODE-2 epilogue.
//   The barrier-free swapped-QK rewrite (R8/R9) NaN'd twice and is shelved.
//   MODE 2 (V^T) previously issued 4096 scattered 2B stores/block at 4KB
//   stride; now stages C^T in the dead As LDS buffer and writes V^T rows as
//   contiguous uint4 pairs (512 x 16B stores/block).
// ---------------------------------------------------------------------------

#define LSEQ 2048
#define HIDDIM 1024
#define NH 16
#define DHD 64
#define NREL 101
#define PMAX 50
#define SCL 0.18033688011112042f   // 0.125 * log2(e)

typedef __attribute__((ext_vector_type(8))) __bf16 bf16x8;
typedef __attribute__((ext_vector_type(4))) float f32x4;

__device__ __forceinline__ unsigned short f2bf(float f) {
  unsigned int u = __builtin_bit_cast(unsigned int, f);
  u += 0x7fffu + ((u >> 16) & 1u);   // RNE
  return (unsigned short)(u >> 16);
}
__device__ __forceinline__ float bflo(unsigned int u) { return __builtin_bit_cast(float, u << 16); }

__device__ __forceinline__ uint4 pack8(float4 f0, float4 f1) {
  uint4 o;
  o.x = (unsigned)f2bf(f0.x) | ((unsigned)f2bf(f0.y) << 16);
  o.y = (unsigned)f2bf(f0.z) | ((unsigned)f2bf(f0.w) << 16);
  o.z = (unsigned)f2bf(f1.x) | ((unsigned)f2bf(f1.y) << 16);
  o.w = (unsigned)f2bf(f1.z) | ((unsigned)f2bf(f1.w) << 16);
  return o;
}

// 4 weights fp32 [1024,1024] -> bf16, one dispatch. 8 elems/thread.
__global__ void cast_w4(const float* __restrict__ s0, const float* __restrict__ s1,
                        const float* __restrict__ s2, const float* __restrict__ s3,
                        unsigned short* __restrict__ dst) {
  const int e = (blockIdx.x * 256 + threadIdx.x) * 8;
  const int g = e >> 20;
  const float* s = (g == 0) ? s0 : (g == 1) ? s1 : (g == 2) ? s2 : s3;
  const int o = e & 0xFFFFF;
  const float4 f0 = *(const float4*)(s + o);
  const float4 f1 = *(const float4*)(s + o + 4);
  *(uint4*)(dst + e) = pack8(f0, f1);
}

// [L,B,HID] fp32 -> row m=(b*L+l) bf16 [4096,1024]
__global__ void cast_x_kernel(const float* __restrict__ src, unsigned short* __restrict__ dst) {
  const int e = (blockIdx.x * 256 + threadIdx.x) * 8;
  const int m = e >> 10, k = e & 1023;
  const int b = m >> 11, l = m & 2047;
  const float* s = src + (size_t)((l << 1) + b) * HIDDIM + k;
  const float4 f0 = *(const float4*)s;
  const float4 f1 = *(const float4*)(s + 4);
  *(uint4*)(dst + e) = pack8(f0, f1);
}

// rel_k fp32 [101][64] -> bf16 [112][64], rows 101..111 zeroed
__global__ void cast_rk_kernel(const float* __restrict__ src, unsigned short* __restrict__ dst) {
  const int e = blockIdx.x * 256 + threadIdx.x;
  if (e >= 112 * 64) return;
  dst[e] = (e < NREL * 64) ? f2bf(src[e]) : (unsigned short)0;
}

// rel_v fp32 [101][64] -> transposed bf16 [64][128]: RVb[d][j], j>=101 zero
__global__ void cast_rv_kernel(const float* __restrict__ src, unsigned short* __restrict__ dst) {
  const int e = blockIdx.x * 256 + threadIdx.x;
  if (e >= 64 * 128) return;
  const int d = e >> 7, j = e & 127;
  dst[e] = (j < NREL) ? f2bf(src[j * DHD + d]) : (unsigned short)0;
}

// C[m,n] = sum_k A[m,k]*W[n,k] + bias[n]
// MODE 0: scatter bf16 [B,H,L,DH]; MODE 1: fp32 [L,B,HID]; MODE 2: bf16 V^T [B,H,DH,L]
template <int MODE>
__global__ __launch_bounds__(256, 4) void gemm64(
    const unsigned short* __restrict__ A,   // [4096,1024] bf16
    const unsigned short* __restrict__ W,   // [1024,1024] bf16
    const float* __restrict__ bias,
    float* __restrict__ outF,
    unsigned short* __restrict__ outB) {
  constexpr int K = 1024;
  __shared__ unsigned short As[64 * 72];
  __shared__ unsigned short Bs[64 * 72];
  const int tid = threadIdx.x;
  const int tm = blockIdx.x >> 4, tn = blockIdx.x & 15;
  const int m0 = tm * 64, n0 = tn * 64;
  const int lane = tid & 63, wave = tid >> 6;
  const int wm = (wave >> 1) * 32, wn = (wave & 1) * 32;
  const int qr = lane & 15, quad = lane >> 4;
  const int sr = tid >> 3, sc = (tid & 7) * 8;
  f32x4 acc[2][2] = {};
  for (int k0 = 0; k0 < K; k0 += 64) {
    *(uint4*)&As[sr * 72 + sc]        = *(const uint4*)&A[(size_t)(m0 + sr) * K + k0 + sc];
    *(uint4*)&As[(sr + 32) * 72 + sc] = *(const uint4*)&A[(size_t)(m0 + sr + 32) * K + k0 + sc];
    *(uint4*)&Bs[sr * 72 + sc]        = *(const uint4*)&W[(size_t)(n0 + sr) * K + k0 + sc];
    *(uint4*)&Bs[(sr + 32) * 72 + sc] = *(const uint4*)&W[(size_t)(n0 + sr + 32) * K + k0 + sc];
    __syncthreads();
#pragma unroll
    for (int ks = 0; ks < 64; ks += 32) {
      bf16x8 a0 = *(const bf16x8*)&As[(wm + qr) * 72 + ks + quad * 8];
      bf16x8 a1 = *(const bf16x8*)&As[(wm + 16 + qr) * 72 + ks + quad * 8];
      bf16x8 b0 = *(const bf16x8*)&Bs[(wn + qr) * 72 + ks + quad * 8];
      bf16x8 b1 = *(const bf16x8*)&Bs[(wn + 16 + qr) * 72 + ks + quad * 8];
      acc[0][0] = __builtin_amdgcn_mfma_f32_16x16x32_bf16(a0, b0, acc[0][0], 0, 0, 0);
      acc[0][1] = __builtin_amdgcn_mfma_f32_16x16x32_bf16(a0, b1, acc[0][1], 0, 0, 0);
      acc[1][0] = __builtin_amdgcn_mfma_f32_16x16x32_bf16(a1, b0, acc[1][0], 0, 0, 0);
      acc[1][1] = __builtin_amdgcn_mfma_f32_16x16x32_bf16(a1, b1, acc[1][1], 0, 0, 0);
    }
    __syncthreads();
  }
  if (MODE == 2) {
    // Stage C^T (bf16) in the dead As buffer: Ct[d=n-local][m-local], pitch 72.
    unsigned short* Ct = As;
#pragma unroll
    for (int i = 0; i < 2; i++)
#pragma unroll
      for (int j = 0; j < 2; j++) {
        const int n = wn + 16 * j + qr;           // local n (= d)
        const float bv = bias[n0 + n];
#pragma unroll
        for (int rr = 0; rr < 4; rr++) {
          const int m = wm + 16 * i + quad * 4 + rr;   // local m (= l-local)
          Ct[n * 72 + m] = f2bf(acc[i][j][rr] + bv);
        }
      }
    __syncthreads();
    // Coalesced write: V^T row d spans 64 contiguous l. 4 threads/row x 32B.
    const int b = m0 >> 11;          // tile never crosses batch (2048 % 64 == 0)
    const int h = n0 >> 6;           // n0 is a multiple of 64
    const int l0 = m0 & 2047;
    const int d = tid >> 2, lc = (tid & 3) * 16;
    unsigned short* dst = outB + (size_t)((b * NH + h) * 64 + d) * LSEQ + l0 + lc;
    const unsigned short* src = Ct + d * 72 + lc;
    *(uint4*)dst       = *(const uint4*)src;
    *(uint4*)(dst + 8) = *(const uint4*)(src + 8);
  } else {
#pragma unroll
    for (int i = 0; i < 2; i++)
#pragma unroll
      for (int j = 0; j < 2; j++) {
        const int n = n0 + wn + 16 * j + qr;      // C/D: col = lane&15
        const float bv = bias[n];
#pragma unroll
        for (int rr = 0; rr < 4; rr++) {
          const int m = m0 + wm + 16 * i + quad * 4 + rr;  // row = quad*4+reg
          const float v = acc[i][j][rr] + bv;
          const int b = m >> 11, l = m & 2047;
          if (MODE == 0) {
            const int h = n >> 6, d = n & 63;
            outB[((size_t)((b * NH + h) * LSEQ + l) << 6) + d] = f2bf(v);
          } else {  // MODE 1
            outF[(size_t)((l << 1) + b) * HIDDIM + n] = v;
          }
        }
      }
  }
}

// ---------------------------------------------------------------------------
// Flash-style MFMA attention (verified R7). Block = one (b,h) x 64 q-rows;
// 4 waves x 16 q. K LDS double-buffered (KT=32, 1 barrier/iter); V
// global-direct early-issue.
// LDS (u16 elems): Kst 2x2304 @0 | Pt 4x(16x44) @4608 | Tb 64x102 @7424 |
//   SrS 64x101 @13952  => 20416 elems = 40,832 B -> 4 blocks/CU.
// ---------------------------------------------------------------------------
#define KT 32
__global__ __launch_bounds__(256, 4) void attn_mfma(
    const unsigned short* __restrict__ Qb,   // [32][2048][64] bf16
    const unsigned short* __restrict__ Kb,   // [32][2048][64] bf16
    const unsigned short* __restrict__ Vgt,  // [32][64][2048] bf16 (V^T)
    const unsigned short* __restrict__ RKb,  // [112][64] bf16, zero-padded
    const unsigned short* __restrict__ RVb,  // [64][128] bf16 (rel_v^T), zero-padded
    unsigned short* __restrict__ outB) {     // [B*L][1024] bf16
  __shared__ __align__(16) unsigned short SH[20416];
  unsigned short* Kst = SH;                  // [2][32*72]
  unsigned short* Tb  = SH + 7424;           // [64][102]
  unsigned short* SrS = SH + 13952;          // [64][101]

  const int tid = threadIdx.x;
  // XCD swizzle: one XCD handles 4 bh entirely (K+V 2MB resident in its L2)
  const int xcd = blockIdx.x & 7, slot = blockIdx.x >> 3;
  const int bh = (slot >> 5) * 8 + xcd;
  const int q0 = (slot & 31) * 64;

  const int lane = tid & 63, wq = tid >> 6;
  const int c = lane & 15, quad = lane >> 4;
  const size_t base = (size_t)bh * (LSEQ * DHD);
  const unsigned short* Qp = Qb + base;
  const unsigned short* Kp = Kb + base;
  const unsigned short* Vp = Vgt + base;
  unsigned short* Ptw = SH + 4608 + wq * 704;   // [16][44] per wave

  const int qrow_w = q0 + wq * 16;    // wave's first global q
  const int srow = quad * 4;          // lane's wave-local row base (+r)
  const int wrow0 = wq * 16 + srow;   // lane's block-local row base (+r)

  // zero own wave's Tb rows
  {
    unsigned* tz = (unsigned*)(Tb + wq * 1632);
    for (int e = lane; e < 816; e += 64) tz[e] = 0u;
  }

  // Q fragments (A-layout: m=lane&15 -> q row, k=quad*8+j)
  const bf16x8 aq0 = *(const bf16x8*)&Qp[(size_t)(qrow_w + c) * DHD + quad * 8];
  const bf16x8 aq1 = *(const bf16x8*)&Qp[(size_t)(qrow_w + c) * DHD + 32 + quad * 8];

  // Sr[q][j] = Q[q]·rel_k[j] via MFMA (unscaled; scale applied in exp2 arg)
#pragma unroll
  for (int jt = 0; jt < 7; jt++) {
    bf16x8 b0 = *(const bf16x8*)&RKb[(jt * 16 + c) * DHD + quad * 8];
    bf16x8 b1 = *(const bf16x8*)&RKb[(jt * 16 + c) * DHD + 32 + quad * 8];
    f32x4 s4 = {};
    s4 = __builtin_amdgcn_mfma_f32_16x16x32_bf16(aq0, b0, s4, 0, 0, 0);
    s4 = __builtin_amdgcn_mfma_f32_16x16x32_bf16(aq1, b1, s4, 0, 0, 0);
    const int jc = jt * 16 + c;
    if (jc < NREL) {
#pragma unroll
      for (int r = 0; r < 4; r++) SrS[(wrow0 + r) * NREL + jc] = f2bf(s4[r]);
    }
  }

  float Srlo[4], Srhi[4];
#pragma unroll
  for (int r = 0; r < 4; r++) {
    Srlo[r] = bflo((unsigned)SrS[(wrow0 + r) * NREL + 0]);
    Srhi[r] = bflo((unsigned)SrS[(wrow0 + r) * NREL + 100]);
  }

  float rsum[4] = {0.f, 0.f, 0.f, 0.f};
  float lows[4] = {0.f, 0.f, 0.f, 0.f}, highs[4] = {0.f, 0.f, 0.f, 0.f};
  f32x4 Od[4] = {};

  const int strow = tid >> 3, stcol = (tid & 7) * 8;   // staging map (32x64 tile)

  // prologue: stage K tile 0 into buf 0
  {
    uint4 k0r = *(const uint4*)&Kp[(size_t)strow * DHD + stcol];
    *(uint4*)&Kst[strow * 72 + stcol] = k0r;
  }
  __syncthreads();

  for (int it = 0; it < 64; ++it) {
    const int k0 = it * KT;
    const int cur = (it & 1) * 2304;
    // issue next K tile's global load + this tile's V frags up front
    uint4 kreg;
    if (it < 63) kreg = *(const uint4*)&Kp[(size_t)(k0 + KT + strow) * DHD + stcol];
    bf16x8 vf[4];
#pragma unroll
    for (int t = 0; t < 4; t++)
      vf[t] = *(const bf16x8*)&Vp[(size_t)(t * 16 + c) * LSEQ + k0 + quad * 8];

    // QK from staged K (B-frag: col = kt*16+c, k-dim = half*32+quad*8)
    const bf16x8 bk00 = *(const bf16x8*)&Kst[cur + c * 72 + quad * 8];
    const bf16x8 bk01 = *(const bf16x8*)&Kst[cur + c * 72 + 32 + quad * 8];
    const bf16x8 bk10 = *(const bf16x8*)&Kst[cur + (16 + c) * 72 + quad * 8];
    const bf16x8 bk11 = *(const bf16x8*)&Kst[cur + (16 + c) * 72 + 32 + quad * 8];
    f32x4 s0 = {}, s1 = {};
    s0 = __builtin_amdgcn_mfma_f32_16x16x32_bf16(aq0, bk00, s0, 0, 0, 0);
    s0 = __builtin_amdgcn_mfma_f32_16x16x32_bf16(aq1, bk01, s0, 0, 0, 0);
    s1 = __builtin_amdgcn_mfma_f32_16x16x32_bf16(aq0, bk10, s1, 0, 0, 0);
    s1 = __builtin_amdgcn_mfma_f32_16x16x32_bf16(aq1, bk11, s1, 0, 0, 0);

    // band mode (wave-uniform): 0 = all j==0, 2 = all j==100, 1 = mixed
    const int mode = (k0 + KT - 1 <= qrow_w - 50) ? 0 : (k0 >= qrow_w + 65) ? 2 : 1;

#pragma unroll
    for (int kt = 0; kt < 2; kt++) {
      const f32x4 s = kt ? s1 : s0;
      const int kcol = k0 + kt * 16 + c;
#pragma unroll
      for (int r = 0; r < 4; r++) {
        float srv;
        int j = -1;
        if (mode == 0) srv = Srlo[r];
        else if (mode == 2) srv = Srhi[r];
        else {
          int dl = kcol - (qrow_w + srow + r);
          dl = dl < -PMAX ? -PMAX : (dl > PMAX ? PMAX : dl);
          j = dl + PMAX;
          srv = bflo((unsigned)SrS[(wrow0 + r) * NREL + j]);
        }
        const float p = exp2f((s[r] + srv) * SCL);
        const unsigned short pb = f2bf(p);
        const float pf = bflo((unsigned)pb);   // quantized p: numerator==denominator
        rsum[r] += pf;
        if (mode == 0) lows[r] += pf;
        else if (mode == 2) highs[r] += pf;
        else {
          if (j == 0) lows[r] += pf;
          else if (j == 100) highs[r] += pf;
          else Tb[(wrow0 + r) * 102 + j] = pb;     // exactly-once store
        }
        Ptw[(srow + r) * 44 + kt * 16 + c] = pb;
      }
    }

    // PV: O[16q x 64d] += P[16q x 32k] · V[32k x 64d]
    const uint2 aplo = *(const uint2*)&Ptw[c * 44 + quad * 8];
    const uint2 aphi = *(const uint2*)&Ptw[c * 44 + quad * 8 + 4];
    const bf16x8 ap = __builtin_bit_cast(bf16x8, (uint4){aplo.x, aplo.y, aphi.x, aphi.y});
#pragma unroll
    for (int t = 0; t < 4; t++)
      Od[t] = __builtin_amdgcn_mfma_f32_16x16x32_bf16(ap, vf[t], Od[t], 0, 0, 0);

    // write next K tile into the other buffer; single barrier per iter
    if (it < 63) *(uint4*)&Kst[(cur ^ 2304) + strow * 72 + stcol] = kreg;
    __syncthreads();
  }

  // reduce row partials over the 16-lane c-groups
#pragma unroll
  for (int m = 1; m < 16; m <<= 1) {
#pragma unroll
    for (int r = 0; r < 4; r++) {
      rsum[r] += __shfl_xor(rsum[r], m, 64);
      lows[r] += __shfl_xor(lows[r], m, 64);
      highs[r] += __shfl_xor(highs[r], m, 64);
    }
  }
  if (c == 0) {
#pragma unroll
    for (int r = 0; r < 4; r++) {
      Tb[(wrow0 + r) * 102 + 0]   = f2bf(lows[r]);    // bucket 0 never stored in loop
      Tb[(wrow0 + r) * 102 + 100] = f2bf(highs[r]);   // bucket 100 likewise
    }
  }
  __syncthreads();   // Tb visibility for cross-lane A-frag reads

  // w2: O += T @ rel_v via MFMA; A-frag gathered scalar from Tb (j>100 -> 0)
#pragma unroll
  for (int kc = 0; kc < 4; kc++) {
    unsigned short a8[8];
#pragma unroll
    for (int jj = 0; jj < 8; jj++) {
      const int j = kc * 32 + quad * 8 + jj;
      a8[jj] = (j <= 100) ? Tb[(wq * 16 + c) * 102 + j] : (unsigned short)0;
    }
    bf16x8 at;
#pragma unroll
    for (int jj = 0; jj < 8; jj++) at[jj] = __builtin_bit_cast(__bf16, a8[jj]);
#pragma unroll
    for (int t = 0; t < 4; t++) {
      const bf16x8 bv = *(const bf16x8*)&RVb[(t * 16 + c) * 128 + kc * 32 + quad * 8];
      Od[t] = __builtin_amdgcn_mfma_f32_16x16x32_bf16(at, bv, Od[t], 0, 0, 0);
    }
  }

  const int b = bh >> 4, h = bh & 15;
#pragma unroll
  for (int r = 0; r < 4; r++) {
    const float inv = 1.f / rsum[r];
    const int qg = q0 + wq * 16 + srow + r;
    unsigned short* op = outB + (size_t)(b * LSEQ + qg) * HIDDIM + h * DHD + c;
#pragma unroll
    for (int t = 0; t < 4; t++) op[t * 16] = f2bf(Od[t][r] * inv);
  }
}

extern "C" void kernel_launch(void* const* d_in, const int* in_sizes, int n_in,
                              void* d_out, int out_size, void* d_ws, size_t ws_size,
                              hipStream_t stream) {
  const float* query = (const float*)d_in[0];
  const float* key   = (const float*)d_in[1];
  const float* value = (const float*)d_in[2];
  const float* Wq = (const float*)d_in[3];  const float* bq = (const float*)d_in[4];
  const float* Wk = (const float*)d_in[5];  const float* bk = (const float*)d_in[6];
  const float* Wv = (const float*)d_in[7];  const float* bv = (const float*)d_in[8];
  const float* Wo = (const float*)d_in[9];  const float* bo = (const float*)d_in[10];
  const float* relk = (const float*)d_in[11];
  const float* relv = (const float*)d_in[12];
  float* out = (float*)d_out;

  // 40 MB workspace layout
  char* w = (char*)d_ws;
  const size_t MB = 1ull << 20;
  unsigned short* Wqb = (unsigned short*)(w + 0 * MB);   // Wcat: 4 x 2MB
  unsigned short* Wkb = (unsigned short*)(w + 2 * MB);
  unsigned short* Wvb = (unsigned short*)(w + 4 * MB);
  unsigned short* Wob = (unsigned short*)(w + 6 * MB);
  unsigned short* Xb  = (unsigned short*)(w + 8 * MB);   // 8MB staging, reused; also AOb
  unsigned short* Qb  = (unsigned short*)(w + 16 * MB);  // [32][2048][64]
  unsigned short* Kb  = (unsigned short*)(w + 24 * MB);
  unsigned short* Vgt = (unsigned short*)(w + 32 * MB);  // [32][64][2048] (V^T)
  unsigned short* AOb = Xb;
  unsigned short* RKb = Wqb;  // rel_k bf16 [112][64]; Wqb dead after Q-gemm
  unsigned short* RVb = Wkb;  // rel_v^T bf16 [64][128]; Wkb dead after K-gemm

  cast_w4<<<2048, 256, 0, stream>>>(Wq, Wk, Wv, Wo, Wqb);

  cast_x_kernel<<<2048, 256, 0, stream>>>(query, Xb);
  gemm64<0><<<1024, 256, 0, stream>>>(Xb, Wqb, bq, nullptr, Qb);
  cast_rk_kernel<<<28, 256, 0, stream>>>(relk, RKb);   // after Q-gemm (aliases Wqb)
  cast_x_kernel<<<2048, 256, 0, stream>>>(key, Xb);
  gemm64<0><<<1024, 256, 0, stream>>>(Xb, Wkb, bk, nullptr, Kb);
  cast_rv_kernel<<<32, 256, 0, stream>>>(relv, RVb);   // after K-gemm (aliases Wkb)
  cast_x_kernel<<<2048, 256, 0, stream>>>(value, Xb);
  gemm64<2><<<1024, 256, 0, stream>>>(Xb, Wvb, bv, nullptr, Vgt);

  attn_mfma<<<1024, 256, 0, stream>>>(Qb, Kb, Vgt, RKb, RVb, AOb);

  gemm64<1><<<1024, 256, 0, stream>>>(AOb, Wob, bo, out, nullptr);
}

// Round 4
// 334.753 us; speedup vs baseline: 1.1665x; 1.1577x over previous
//
#include <hip/hip_runtime.h>

// ---------------------------------------------------------------------------
// RelativeAttention: L=2048, B=2, HID=1024, H=16, DH=64, P=50
//   q,k,v = x @ W^T + b            (bf16 MFMA GEMM, fp32 accumulate)
//   attn  = softmax((QK^T + Sr_gather)/8),  Sr[q,j] = Q[q]·rel_k[j]
//   out_h = attn@V + T@rel_v,      T[q,j] = sum of p over bucket j
//   out   = out_h @ Wo^T + bo      (written [L,B,HID])
// R11 = R7 attention (verified) + consolidated front-end:
//   - cast_x3: one dispatch casts query/key/value (Xk,Xv scratch in d_out).
//   - gemm_qkv: ONE dispatch, 3x256 blocks, 128x128 tile, BK=64, 4 waves of
//     64x64. global_load_lds width-16 staging with XOR bank-swizzle applied
//     to the GLOBAL SOURCE column (LDS dest linear, rule #21) and to the
//     ds_read address: col ^= ((row&7)<<4) bytes -> 2-way banks.
//     Accumulation order identical to gemm64 -> bitwise-same Q/K/V.
//   - V^T epilogue: LDS transpose + coalesced uint4 stores (R10, verified).
//   - 7 dispatches total (was 10).
// ---------------------------------------------------------------------------

#define LSEQ 2048
#define HIDDIM 1024
#define NH 16
#define DHD 64
#define NREL 101
#define PMAX 50
#define SCL 0.18033688011112042f   // 0.125 * log2(e)

typedef __attribute__((ext_vector_type(8))) __bf16 bf16x8;
typedef __attribute__((ext_vector_type(4))) float f32x4;

#define MFMA(A, B, C) __builtin_amdgcn_mfma_f32_16x16x32_bf16(A, B, C, 0, 0, 0)

__device__ __forceinline__ unsigned short f2bf(float f) {
  unsigned int u = __builtin_bit_cast(unsigned int, f);
  u += 0x7fffu + ((u >> 16) & 1u);   // RNE
  return (unsigned short)(u >> 16);
}
__device__ __forceinline__ float bflo(unsigned int u) { return __builtin_bit_cast(float, u << 16); }

__device__ __forceinline__ uint4 pack8(float4 f0, float4 f1) {
  uint4 o;
  o.x = (unsigned)f2bf(f0.x) | ((unsigned)f2bf(f0.y) << 16);
  o.y = (unsigned)f2bf(f0.z) | ((unsigned)f2bf(f0.w) << 16);
  o.z = (unsigned)f2bf(f1.x) | ((unsigned)f2bf(f1.y) << 16);
  o.w = (unsigned)f2bf(f1.z) | ((unsigned)f2bf(f1.w) << 16);
  return o;
}

// async global->LDS, 16B per lane, wave-uniform LDS base + lane*16
__device__ __forceinline__ void gload16(const unsigned short* g, unsigned short* l) {
  __builtin_amdgcn_global_load_lds(
      (const __attribute__((address_space(1))) unsigned int*)g,
      (__attribute__((address_space(3))) unsigned int*)l, 16, 0, 0);
}

// 4 weights fp32 [1024,1024] -> bf16, one dispatch. 8 elems/thread.
__global__ void cast_w4(const float* __restrict__ s0, const float* __restrict__ s1,
                        const float* __restrict__ s2, const float* __restrict__ s3,
                        unsigned short* __restrict__ dst) {
  const int e = (blockIdx.x * 256 + threadIdx.x) * 8;
  const int g = e >> 20;
  const float* s = (g == 0) ? s0 : (g == 1) ? s1 : (g == 2) ? s2 : s3;
  const int o = e & 0xFFFFF;
  const float4 f0 = *(const float4*)(s + o);
  const float4 f1 = *(const float4*)(s + o + 4);
  *(uint4*)(dst + e) = pack8(f0, f1);
}

// query/key/value [L,B,HID] fp32 -> bf16 [4096,1024] (row m = b*L+l), one dispatch
__global__ void cast_x3(const float* __restrict__ q, const float* __restrict__ k,
                        const float* __restrict__ v,
                        unsigned short* __restrict__ dq, unsigned short* __restrict__ dk,
                        unsigned short* __restrict__ dv) {
  const int gid = blockIdx.x * 256 + threadIdx.x;
  const int segi = gid >> 19;                   // 2^19 threads per input (4M elems / 8)
  const int e = (gid & 0x7FFFF) * 8;
  const float* s = (segi == 0) ? q : (segi == 1) ? k : v;
  unsigned short* dst = (segi == 0) ? dq : (segi == 1) ? dk : dv;
  const int m = e >> 10, kk = e & 1023;
  const int b = m >> 11, l = m & 2047;
  const float* sp = s + (size_t)((l << 1) + b) * HIDDIM + kk;
  const float4 f0 = *(const float4*)sp;
  const float4 f1 = *(const float4*)(sp + 4);
  *(uint4*)(dst + e) = pack8(f0, f1);
}

// rel_k fp32 [101][64] -> bf16 [112][64], rows 101..111 zeroed
__global__ void cast_rk_kernel(const float* __restrict__ src, unsigned short* __restrict__ dst) {
  const int e = blockIdx.x * 256 + threadIdx.x;
  if (e >= 112 * 64) return;
  dst[e] = (e < NREL * 64) ? f2bf(src[e]) : (unsigned short)0;
}

// rel_v fp32 [101][64] -> transposed bf16 [64][128]: RVb[d][j], j>=101 zero
__global__ void cast_rv_kernel(const float* __restrict__ src, unsigned short* __restrict__ dst) {
  const int e = blockIdx.x * 256 + threadIdx.x;
  if (e >= 64 * 128) return;
  const int d = e >> 7, j = e & 127;
  dst[e] = (j < NREL) ? f2bf(src[j * DHD + d]) : (unsigned short)0;
}

// ---------------------------------------------------------------------------
// Fused Q/K/V projection. grid = 3*256; seg = bid>>8 picks {Q,K,V}.
// 128x128 tile, BK=64, 4 waves (2x2) each computing 64x64 (4x4 MFMA frags).
// Staging: global_load_lds w16, LDS [128][64] bf16 linear; bank swizzle via
// inverse-swizzled SOURCE col (byte col ^= ((row&7)<<4)) + swizzled ds_read.
// Epilogue: seg 0/1 scatter bf16 [B,H,L,DH]; seg 2 LDS-transpose -> V^T.
// ---------------------------------------------------------------------------
__global__ __launch_bounds__(256, 3) void gemm_qkv(
    const unsigned short* __restrict__ Xq, const unsigned short* __restrict__ Xk,
    const unsigned short* __restrict__ Xv, const unsigned short* __restrict__ Wcat,
    const float* __restrict__ bq, const float* __restrict__ bk, const float* __restrict__ bv,
    unsigned short* __restrict__ Qb, unsigned short* __restrict__ Kb,
    unsigned short* __restrict__ Vgt) {
  __shared__ __align__(16) unsigned short SH[17408];   // 34816 B (also Ct 128x136)
  unsigned short* LA = SH;           // [128][64] bf16, swizzled content
  unsigned short* LB = SH + 8192;

  const int tid = threadIdx.x;
  const int seg = blockIdx.x >> 8;
  const int t = blockIdx.x & 255;
  const int m0 = (t >> 3) * 128, n0 = (t & 7) * 128;

  const unsigned short* A = (seg == 0) ? Xq : (seg == 1) ? Xk : Xv;
  const unsigned short* W = Wcat + ((size_t)seg << 20);
  const float* bias = (seg == 0) ? bq : (seg == 1) ? bk : bv;

  const int lane = tid & 63, w = tid >> 6;
  const int c = lane & 15, quad = lane >> 4;

  // staging maps: lane covers LDS bytes [i*1024 + lane*16, +16) of wave slice.
  // row = w*32 + i*8 + (lane>>3); row&7 == lane>>3 (i*8, w*32 are mult of 8).
  // source col pre-swizzled: colbyte = ((lane&7)<<4) ^ ((lane>>3)<<4).
  const int srow = w * 32 + (lane >> 3);
  const int scol = ((lane & 7) ^ (lane >> 3)) << 3;    // elems
  const unsigned short* pA = A + (size_t)(m0 + srow) * 1024 + scol;
  const unsigned short* pW = W + (size_t)(n0 + srow) * 1024 + scol;
  unsigned short* lA = LA + w * 2048;
  unsigned short* lB = LB + w * 2048;

  const int wr = w >> 1, wc = w & 1;
  const int cx = (c & 7) << 3;                         // frag-read XOR (elems)

  f32x4 acc[4][4] = {};

  for (int k0 = 0; k0 < 1024; k0 += 64) {
#pragma unroll
    for (int i = 0; i < 4; i++) {
      gload16(pA + k0 + i * 8192, lA + i * 512);
      gload16(pW + k0 + i * 8192, lB + i * 512);
    }
    __syncthreads();   // drains vmcnt: staged data visible
#pragma unroll
    for (int ks = 0; ks < 2; ks++) {
      bf16x8 af[4], bfr[4];
#pragma unroll
      for (int f = 0; f < 4; f++) {
        af[f]  = *(const bf16x8*)&LA[(wr * 64 + f * 16 + c) * 64 + ((ks * 32 + quad * 8) ^ cx)];
        bfr[f] = *(const bf16x8*)&LB[(wc * 64 + f * 16 + c) * 64 + ((ks * 32 + quad * 8) ^ cx)];
      }
#pragma unroll
      for (int i = 0; i < 4; i++)
#pragma unroll
        for (int j = 0; j < 4; j++)
          acc[i][j] = MFMA(af[i], bfr[j], acc[i][j]);
    }
    __syncthreads();
  }

  const int b = m0 >> 11, l0 = m0 & 2047;   // tile never crosses batch (2048%128==0)
  const int h0 = n0 >> 6;
  if (seg < 2) {
    unsigned short* out = seg ? Kb : Qb;
#pragma unroll
    for (int i = 0; i < 4; i++)
#pragma unroll
      for (int j = 0; j < 4; j++) {
        const int nl = wc * 64 + j * 16 + c;            // C/D col = lane&15
        const float bv_ = bias[n0 + nl];
        const int h = h0 + (nl >> 6), d = nl & 63;
#pragma unroll
        for (int r = 0; r < 4; r++) {                   // C/D row = quad*4+r
          const int l = l0 + wr * 64 + i * 16 + quad * 4 + r;
          out[((size_t)((b * NH + h) * LSEQ + l) << 6) + d] = f2bf(acc[i][j][r] + bv_);
        }
      }
  } else {
    // stage C^T bf16 in LDS (staging buffers dead): Ct[n_local][m_local], pitch 136
    unsigned short* Ct = SH;
#pragma unroll
    for (int i = 0; i < 4; i++)
#pragma unroll
      for (int j = 0; j < 4; j++) {
        const int nl = wc * 64 + j * 16 + c;
        const float bv_ = bias[n0 + nl];
#pragma unroll
        for (int r = 0; r < 4; r++) {
          const int ml = wr * 64 + i * 16 + quad * 4 + r;
          Ct[nl * 136 + ml] = f2bf(acc[i][j][r] + bv_);
        }
      }
    __syncthreads();
    // coalesced V^T write: 2 threads per d-row, 128B each
    const int dr = tid >> 1, lc = (tid & 1) * 64;
    const int h = h0 + (dr >> 6), dd = dr & 63;
    unsigned short* dst = Vgt + ((size_t)((b * NH + h) * 64 + dd)) * LSEQ + l0 + lc;
    const unsigned short* src = Ct + dr * 136 + lc;
#pragma unroll
    for (int u = 0; u < 8; u++)
      *(uint4*)(dst + u * 8) = *(const uint4*)(src + u * 8);
  }
}

// C[m,n] = sum_k A[m,k]*W[n,k] + bias[n]; MODE 1: fp32 [L,B,HID] (output GEMM)
template <int MODE>
__global__ __launch_bounds__(256, 4) void gemm64(
    const unsigned short* __restrict__ A,   // [4096,1024] bf16
    const unsigned short* __restrict__ W,   // [1024,1024] bf16
    const float* __restrict__ bias,
    float* __restrict__ outF,
    unsigned short* __restrict__ outB) {
  constexpr int K = 1024;
  __shared__ unsigned short As[64 * 72];
  __shared__ unsigned short Bs[64 * 72];
  const int tid = threadIdx.x;
  const int tm = blockIdx.x >> 4, tn = blockIdx.x & 15;
  const int m0 = tm * 64, n0 = tn * 64;
  const int lane = tid & 63, wave = tid >> 6;
  const int wm = (wave >> 1) * 32, wn = (wave & 1) * 32;
  const int qr = lane & 15, quad = lane >> 4;
  const int sr = tid >> 3, sc = (tid & 7) * 8;
  f32x4 acc[2][2] = {};
  for (int k0 = 0; k0 < K; k0 += 64) {
    *(uint4*)&As[sr * 72 + sc]        = *(const uint4*)&A[(size_t)(m0 + sr) * K + k0 + sc];
    *(uint4*)&As[(sr + 32) * 72 + sc] = *(const uint4*)&A[(size_t)(m0 + sr + 32) * K + k0 + sc];
    *(uint4*)&Bs[sr * 72 + sc]        = *(const uint4*)&W[(size_t)(n0 + sr) * K + k0 + sc];
    *(uint4*)&Bs[(sr + 32) * 72 + sc] = *(const uint4*)&W[(size_t)(n0 + sr + 32) * K + k0 + sc];
    __syncthreads();
#pragma unroll
    for (int ks = 0; ks < 64; ks += 32) {
      bf16x8 a0 = *(const bf16x8*)&As[(wm + qr) * 72 + ks + quad * 8];
      bf16x8 a1 = *(const bf16x8*)&As[(wm + 16 + qr) * 72 + ks + quad * 8];
      bf16x8 b0 = *(const bf16x8*)&Bs[(wn + qr) * 72 + ks + quad * 8];
      bf16x8 b1 = *(const bf16x8*)&Bs[(wn + 16 + qr) * 72 + ks + quad * 8];
      acc[0][0] = MFMA(a0, b0, acc[0][0]);
      acc[0][1] = MFMA(a0, b1, acc[0][1]);
      acc[1][0] = MFMA(a1, b0, acc[1][0]);
      acc[1][1] = MFMA(a1, b1, acc[1][1]);
    }
    __syncthreads();
  }
#pragma unroll
  for (int i = 0; i < 2; i++)
#pragma unroll
    for (int j = 0; j < 2; j++) {
      const int n = n0 + wn + 16 * j + qr;      // C/D: col = lane&15
      const float bv = bias[n];
#pragma unroll
      for (int rr = 0; rr < 4; rr++) {
        const int m = m0 + wm + 16 * i + quad * 4 + rr;  // row = quad*4+reg
        const float v = acc[i][j][rr] + bv;
        const int b = m >> 11, l = m & 2047;
        if (MODE == 1) {
          outF[(size_t)((l << 1) + b) * HIDDIM + n] = v;
        }
      }
    }
}

// ---------------------------------------------------------------------------
// Flash-style MFMA attention (verified R7, untouched). Block = one (b,h) x 64
// q-rows; 4 waves x 16 q. K LDS double-buffered; V global-direct early-issue.
// ---------------------------------------------------------------------------
#define KT 32
__global__ __launch_bounds__(256, 4) void attn_mfma(
    const unsigned short* __restrict__ Qb,   // [32][2048][64] bf16
    const unsigned short* __restrict__ Kb,   // [32][2048][64] bf16
    const unsigned short* __restrict__ Vgt,  // [32][64][2048] bf16 (V^T)
    const unsigned short* __restrict__ RKb,  // [112][64] bf16, zero-padded
    const unsigned short* __restrict__ RVb,  // [64][128] bf16 (rel_v^T), zero-padded
    unsigned short* __restrict__ outB) {     // [B*L][1024] bf16
  __shared__ __align__(16) unsigned short SH[20416];
  unsigned short* Kst = SH;                  // [2][32*72]
  unsigned short* Tb  = SH + 7424;           // [64][102]
  unsigned short* SrS = SH + 13952;          // [64][101]

  const int tid = threadIdx.x;
  const int xcd = blockIdx.x & 7, slot = blockIdx.x >> 3;
  const int bh = (slot >> 5) * 8 + xcd;
  const int q0 = (slot & 31) * 64;

  const int lane = tid & 63, wq = tid >> 6;
  const int c = lane & 15, quad = lane >> 4;
  const size_t base = (size_t)bh * (LSEQ * DHD);
  const unsigned short* Qp = Qb + base;
  const unsigned short* Kp = Kb + base;
  const unsigned short* Vp = Vgt + base;
  unsigned short* Ptw = SH + 4608 + wq * 704;   // [16][44] per wave

  const int qrow_w = q0 + wq * 16;
  const int srow = quad * 4;
  const int wrow0 = wq * 16 + srow;

  {
    unsigned* tz = (unsigned*)(Tb + wq * 1632);
    for (int e = lane; e < 816; e += 64) tz[e] = 0u;
  }

  const bf16x8 aq0 = *(const bf16x8*)&Qp[(size_t)(qrow_w + c) * DHD + quad * 8];
  const bf16x8 aq1 = *(const bf16x8*)&Qp[(size_t)(qrow_w + c) * DHD + 32 + quad * 8];

#pragma unroll
  for (int jt = 0; jt < 7; jt++) {
    bf16x8 b0 = *(const bf16x8*)&RKb[(jt * 16 + c) * DHD + quad * 8];
    bf16x8 b1 = *(const bf16x8*)&RKb[(jt * 16 + c) * DHD + 32 + quad * 8];
    f32x4 s4 = {};
    s4 = MFMA(aq0, b0, s4);
    s4 = MFMA(aq1, b1, s4);
    const int jc = jt * 16 + c;
    if (jc < NREL) {
#pragma unroll
      for (int r = 0; r < 4; r++) SrS[(wrow0 + r) * NREL + jc] = f2bf(s4[r]);
    }
  }

  float Srlo[4], Srhi[4];
#pragma unroll
  for (int r = 0; r < 4; r++) {
    Srlo[r] = bflo((unsigned)SrS[(wrow0 + r) * NREL + 0]);
    Srhi[r] = bflo((unsigned)SrS[(wrow0 + r) * NREL + 100]);
  }

  float rsum[4] = {0.f, 0.f, 0.f, 0.f};
  float lows[4] = {0.f, 0.f, 0.f, 0.f}, highs[4] = {0.f, 0.f, 0.f, 0.f};
  f32x4 Od[4] = {};

  const int strow = tid >> 3, stcol = (tid & 7) * 8;

  {
    uint4 k0r = *(const uint4*)&Kp[(size_t)strow * DHD + stcol];
    *(uint4*)&Kst[strow * 72 + stcol] = k0r;
  }
  __syncthreads();

  for (int it = 0; it < 64; ++it) {
    const int k0 = it * KT;
    const int cur = (it & 1) * 2304;
    uint4 kreg;
    if (it < 63) kreg = *(const uint4*)&Kp[(size_t)(k0 + KT + strow) * DHD + stcol];
    bf16x8 vf[4];
#pragma unroll
    for (int t = 0; t < 4; t++)
      vf[t] = *(const bf16x8*)&Vp[(size_t)(t * 16 + c) * LSEQ + k0 + quad * 8];

    const bf16x8 bk00 = *(const bf16x8*)&Kst[cur + c * 72 + quad * 8];
    const bf16x8 bk01 = *(const bf16x8*)&Kst[cur + c * 72 + 32 + quad * 8];
    const bf16x8 bk10 = *(const bf16x8*)&Kst[cur + (16 + c) * 72 + quad * 8];
    const bf16x8 bk11 = *(const bf16x8*)&Kst[cur + (16 + c) * 72 + 32 + quad * 8];
    f32x4 s0 = {}, s1 = {};
    s0 = MFMA(aq0, bk00, s0);
    s0 = MFMA(aq1, bk01, s0);
    s1 = MFMA(aq0, bk10, s1);
    s1 = MFMA(aq1, bk11, s1);

    const int mode = (k0 + KT - 1 <= qrow_w - 50) ? 0 : (k0 >= qrow_w + 65) ? 2 : 1;

#pragma unroll
    for (int kt = 0; kt < 2; kt++) {
      const f32x4 s = kt ? s1 : s0;
      const int kcol = k0 + kt * 16 + c;
#pragma unroll
      for (int r = 0; r < 4; r++) {
        float srv;
        int j = -1;
        if (mode == 0) srv = Srlo[r];
        else if (mode == 2) srv = Srhi[r];
        else {
          int dl = kcol - (qrow_w + srow + r);
          dl = dl < -PMAX ? -PMAX : (dl > PMAX ? PMAX : dl);
          j = dl + PMAX;
          srv = bflo((unsigned)SrS[(wrow0 + r) * NREL + j]);
        }
        const float p = exp2f((s[r] + srv) * SCL);
        const unsigned short pb = f2bf(p);
        const float pf = bflo((unsigned)pb);
        rsum[r] += pf;
        if (mode == 0) lows[r] += pf;
        else if (mode == 2) highs[r] += pf;
        else {
          if (j == 0) lows[r] += pf;
          else if (j == 100) highs[r] += pf;
          else Tb[(wrow0 + r) * 102 + j] = pb;
        }
        Ptw[(srow + r) * 44 + kt * 16 + c] = pb;
      }
    }

    const uint2 aplo = *(const uint2*)&Ptw[c * 44 + quad * 8];
    const uint2 aphi = *(const uint2*)&Ptw[c * 44 + quad * 8 + 4];
    const bf16x8 ap = __builtin_bit_cast(bf16x8, (uint4){aplo.x, aplo.y, aphi.x, aphi.y});
#pragma unroll
    for (int t = 0; t < 4; t++)
      Od[t] = MFMA(ap, vf[t], Od[t]);

    if (it < 63) *(uint4*)&Kst[(cur ^ 2304) + strow * 72 + stcol] = kreg;
    __syncthreads();
  }

#pragma unroll
  for (int m = 1; m < 16; m <<= 1) {
#pragma unroll
    for (int r = 0; r < 4; r++) {
      rsum[r] += __shfl_xor(rsum[r], m, 64);
      lows[r] += __shfl_xor(lows[r], m, 64);
      highs[r] += __shfl_xor(highs[r], m, 64);
    }
  }
  if (c == 0) {
#pragma unroll
    for (int r = 0; r < 4; r++) {
      Tb[(wrow0 + r) * 102 + 0]   = f2bf(lows[r]);
      Tb[(wrow0 + r) * 102 + 100] = f2bf(highs[r]);
    }
  }
  __syncthreads();

#pragma unroll
  for (int kc = 0; kc < 4; kc++) {
    unsigned short a8[8];
#pragma unroll
    for (int jj = 0; jj < 8; jj++) {
      const int j = kc * 32 + quad * 8 + jj;
      a8[jj] = (j <= 100) ? Tb[(wq * 16 + c) * 102 + j] : (unsigned short)0;
    }
    bf16x8 at;
#pragma unroll
    for (int jj = 0; jj < 8; jj++) at[jj] = __builtin_bit_cast(__bf16, a8[jj]);
#pragma unroll
    for (int t = 0; t < 4; t++) {
      const bf16x8 bv = *(const bf16x8*)&RVb[(t * 16 + c) * 128 + kc * 32 + quad * 8];
      Od[t] = MFMA(at, bv, Od[t]);
    }
  }

  const int b = bh >> 4, h = bh & 15;
#pragma unroll
  for (int r = 0; r < 4; r++) {
    const float inv = 1.f / rsum[r];
    const int qg = q0 + wq * 16 + srow + r;
    unsigned short* op = outB + (size_t)(b * LSEQ + qg) * HIDDIM + h * DHD + c;
#pragma unroll
    for (int t = 0; t < 4; t++) op[t * 16] = f2bf(Od[t][r] * inv);
  }
}

extern "C" void kernel_launch(void* const* d_in, const int* in_sizes, int n_in,
                              void* d_out, int out_size, void* d_ws, size_t ws_size,
                              hipStream_t stream) {
  const float* query = (const float*)d_in[0];
  const float* key   = (const float*)d_in[1];
  const float* value = (const float*)d_in[2];
  const float* Wq = (const float*)d_in[3];  const float* bq = (const float*)d_in[4];
  const float* Wk = (const float*)d_in[5];  const float* bk = (const float*)d_in[6];
  const float* Wv = (const float*)d_in[7];  const float* bv = (const float*)d_in[8];
  const float* Wo = (const float*)d_in[9];  const float* bo = (const float*)d_in[10];
  const float* relk = (const float*)d_in[11];
  const float* relv = (const float*)d_in[12];
  float* out = (float*)d_out;

  // 40 MB workspace layout
  char* w = (char*)d_ws;
  const size_t MB = 1ull << 20;
  unsigned short* Wcat = (unsigned short*)(w + 0 * MB);  // Wq,Wk,Wv,Wo at 0/2/4/6 MB
  unsigned short* Wob  = (unsigned short*)(w + 6 * MB);
  unsigned short* Xq   = (unsigned short*)(w + 8 * MB);  // 8 MB; reused as AOb
  unsigned short* Qb   = (unsigned short*)(w + 16 * MB); // [32][2048][64]
  unsigned short* Kb   = (unsigned short*)(w + 24 * MB);
  unsigned short* Vgt  = (unsigned short*)(w + 32 * MB); // [32][64][2048] (V^T)
  unsigned short* AOb  = Xq;
  unsigned short* RKb  = Wcat;                            // aliases Wq (dead post-QKV)
  unsigned short* RVb  = (unsigned short*)(w + 2 * MB);   // aliases Wk (dead post-QKV)
  // Xk/Xv scratch inside d_out (16 MB fp32, fully overwritten by final GEMM)
  unsigned short* Xk = (unsigned short*)out;
  unsigned short* Xv = (unsigned short*)out + (4u << 20);

  cast_w4<<<2048, 256, 0, stream>>>(Wq, Wk, Wv, Wo, Wcat);
  cast_x3<<<6144, 256, 0, stream>>>(query, key, value, Xq, Xk, Xv);
  gemm_qkv<<<768, 256, 0, stream>>>(Xq, Xk, Xv, Wcat, bq, bk, bv, Qb, Kb, Vgt);
  cast_rk_kernel<<<28, 256, 0, stream>>>(relk, RKb);   // after QKV gemm (aliases Wq)
  cast_rv_kernel<<<32, 256, 0, stream>>>(relv, RVb);   // after QKV gemm (aliases Wk)
  attn_mfma<<<1024, 256, 0, stream>>>(Qb, Kb, Vgt, RKb, RVb, AOb);
  gemm64<1><<<1024, 256, 0, stream>>>(AOb, Wob, bo, out, nullptr);
}